// Round 15
// baseline (411.733 us; speedup 1.0000x reference)
//
#include <hip/hip_runtime.h>
#include <stdint.h>

#define N_TRIP 200000
#define N_ENT  200000
#define N_REL  500
#define D      128
#define MARGINF 6.0f
#define BN_EPSF 1e-5f
#define PHASE_C 50.26548245743669f   // PI / REL_RANGE, REL_RANGE = 8/128
#define STAT_BLKS 256
#define BN1_BLKS  240

typedef unsigned short u16;
typedef unsigned int   u32;
typedef unsigned long long u64;
typedef __attribute__((ext_vector_type(8))) short short8;
typedef __attribute__((ext_vector_type(4))) float f32x4;
typedef __attribute__((ext_vector_type(4))) unsigned short u16x4;

__device__ inline float bfl(u32 u){ return __uint_as_float(u<<16); }
__device__ inline float bfh(u32 u){ return __uint_as_float(u&0xffff0000u); }
__device__ inline float bfu(u16 u){ return __uint_as_float(((u32)u)<<16); }
__device__ inline u16 f2bf(float f){
  u32 u = __float_as_uint(f);
  u32 r = (u + 0x7fffu + ((u>>16)&1u))>>16;
  return (u16)r;
}

// ------- K1: histogram; rel counts aggregated in LDS ------------------------
__global__ __launch_bounds__(256) void k_hist(const int* __restrict__ trip,
    int* __restrict__ cnt0, int* __restrict__ cnt1, int* __restrict__ cntr){
  __shared__ int rc[N_REL];
  int t = threadIdx.x;
  for(int r=t; r<N_REL; r+=256) rc[r]=0;
  __syncthreads();
  #pragma unroll
  for(int k=0;k<8;k++){
    int i = blockIdx.x*2048 + t + k*256;
    if(i < N_TRIP){
      atomicAdd(&cnt0[trip[3*i]],   1);
      atomicAdd(&cnt1[trip[3*i+1]], 1);
      atomicAdd(&rc[trip[3*i+2]],   1);
    }
  }
  __syncthreads();
  for(int r=t; r<N_REL; r+=256){
    int c = rc[r];
    if(c) atomicAdd(&cntr[r], c);
  }
}

// ---------------- CSR build: 3-kernel prefix scan + cursor scatter ----------
__global__ __launch_bounds__(1024) void k_scan1(const int* __restrict__ cnt0,
    const int* __restrict__ cnt1, int* __restrict__ offs, int* __restrict__ bsum){
  __shared__ int sh[1024];
  int t = threadIdx.x;
  int e = blockIdx.x*1024 + t;
  int d = (e < N_ENT) ? cnt0[e] + cnt1[e] : 0;
  sh[t] = d; __syncthreads();
  for(int st=1; st<1024; st<<=1){
    int x = (t>=st) ? sh[t-st] : 0;
    __syncthreads();
    sh[t] += x;
    __syncthreads();
  }
  if(e < N_ENT) offs[e] = sh[t] - d;
  if(t == 1023) bsum[blockIdx.x] = sh[t];
}

__global__ __launch_bounds__(512) void k_scan2(const int* __restrict__ bsum,
    int* __restrict__ boffs, const int* __restrict__ cntr,
    int* __restrict__ roffs, int* __restrict__ rcur, int nblk){
  __shared__ int sh[512];
  int t = threadIdx.x;
  int v = (t < nblk) ? bsum[t] : 0;
  sh[t] = v; __syncthreads();
  for(int st=1; st<512; st<<=1){
    int x = (t>=st) ? sh[t-st] : 0;
    __syncthreads(); sh[t] += x; __syncthreads();
  }
  if(t < nblk) boffs[t] = sh[t] - v;
  __syncthreads();
  int w = (t < N_REL) ? cntr[t] : 0;
  sh[t] = w; __syncthreads();
  for(int st=1; st<512; st<<=1){
    int x = (t>=st) ? sh[t-st] : 0;
    __syncthreads(); sh[t] += x; __syncthreads();
  }
  if(t < N_REL){ roffs[t] = sh[t]-w; rcur[t] = sh[t]-w; }
}

__global__ __launch_bounds__(1024) void k_scan3(int* __restrict__ offs,
    const int* __restrict__ boffs, int* __restrict__ cur){
  int e = blockIdx.x*1024 + threadIdx.x;
  if(e < N_ENT){
    int o = offs[e] + boffs[blockIdx.x];
    offs[e] = o;
    cur[e] = o;
  }
}

// ------- K-edges: chunked scatter; rel cursors via LDS + bulk alloc ---------
__global__ __launch_bounds__(256) void k_edges(const int* __restrict__ trip,
    int* __restrict__ cur, int* __restrict__ rcur,
    u32* __restrict__ ebuf, u64* __restrict__ pair64, u64* __restrict__ rpair){
  __shared__ int rcnt[N_REL];
  __shared__ int rbase[N_REL];
  int t = threadIdx.x;
  for(int r=t; r<N_REL; r+=256) rcnt[r]=0;
  __syncthreads();
  int i0 = blockIdx.x*2048;
  int lt0[8], lt1[8], lt2[8], lp[8];
  #pragma unroll
  for(int k=0;k<8;k++){
    int i = i0 + t + k*256;
    lt2[k] = -1;
    if(i < N_TRIP){
      int t0 = trip[3*i], t1 = trip[3*i+1], t2 = trip[3*i+2];
      lt0[k]=t0; lt1[k]=t1; lt2[k]=t2;
      lp[k] = atomicAdd(&rcnt[t2], 1);
      pair64[i] = ((u64)t2<<36) | ((u64)t1<<18) | (u64)t0;
      ebuf[atomicAdd(&cur[t0], 1)] = ((u32)t1<<10) | ((u32)t2<<1);
      ebuf[atomicAdd(&cur[t1], 1)] = ((u32)t0<<10) | ((u32)t2<<1) | 1u;
    }
  }
  __syncthreads();
  for(int r=t; r<N_REL; r+=256){
    int c = rcnt[r];
    rbase[r] = c ? atomicAdd(&rcur[r], c) : 0;
  }
  __syncthreads();
  #pragma unroll
  for(int k=0;k<8;k++){
    if(lt2[k] >= 0)
      rpair[rbase[lt2[k]] + lp[k]] =
        ((u64)lt2[k]<<36) | ((u64)lt1[k]<<18) | (u64)lt0[k];
  }
}

// ------- K2a: PURE streaming prep: ent -> entnbf (+optional raw entbf) ------
__global__ __launch_bounds__(256) void k_prep(const float* __restrict__ ent,
    u32* __restrict__ entnbf, u32* entbf){
  int t = threadIdx.x, lane = t & 63;
  int l16 = lane & 15, g = lane >> 4;
  int wid = blockIdx.x*4 + (t>>6), nw = gridDim.x*4;
  for(int e8 = wid*8; e8 < N_ENT; e8 += nw*8){
    int eA = e8 + g, eB = e8 + 4 + g;
    const float* xpA = ent + (size_t)eA*D + l16*8;
    const float* xpB = ent + (size_t)eB*D + l16*8;
    float4 a0 = *(const float4*)xpA;
    float4 a1 = *(const float4*)(xpA+4);
    float4 b0 = *(const float4*)xpB;
    float4 b1 = *(const float4*)(xpB+4);
    if(entbf){
      uint4 pa, pb;
      pa.x = (u32)f2bf(a0.x) | ((u32)f2bf(a0.y)<<16);
      pa.y = (u32)f2bf(a0.z) | ((u32)f2bf(a0.w)<<16);
      pa.z = (u32)f2bf(a1.x) | ((u32)f2bf(a1.y)<<16);
      pa.w = (u32)f2bf(a1.z) | ((u32)f2bf(a1.w)<<16);
      pb.x = (u32)f2bf(b0.x) | ((u32)f2bf(b0.y)<<16);
      pb.y = (u32)f2bf(b0.z) | ((u32)f2bf(b0.w)<<16);
      pb.z = (u32)f2bf(b1.x) | ((u32)f2bf(b1.y)<<16);
      pb.w = (u32)f2bf(b1.z) | ((u32)f2bf(b1.w)<<16);
      *(uint4*)(entbf + (size_t)eA*64 + l16*4) = pa;
      *(uint4*)(entbf + (size_t)eB*64 + l16*4) = pb;
    }
    float ssA = a0.x*a0.x + a0.y*a0.y + a0.z*a0.z + a0.w*a0.w
              + a1.x*a1.x + a1.y*a1.y + a1.z*a1.z + a1.w*a1.w;
    float ssB = b0.x*b0.x + b0.y*b0.y + b0.z*b0.z + b0.w*b0.w
              + b1.x*b1.x + b1.y*b1.y + b1.z*b1.z + b1.w*b1.w;
    #pragma unroll
    for(int o=8;o>0;o>>=1){
      ssA += __shfl_xor(ssA,o,64);
      ssB += __shfl_xor(ssB,o,64);
    }
    float nA = sqrtf(ssA), nB = sqrtf(ssB);
    float scA = nA > 1.0f ? 1.0f/nA : 1.0f;
    float scB = nB > 1.0f ? 1.0f/nB : 1.0f;
    uint4 na, nb;
    na.x = (u32)f2bf(a0.x*scA) | ((u32)f2bf(a0.y*scA)<<16);
    na.y = (u32)f2bf(a0.z*scA) | ((u32)f2bf(a0.w*scA)<<16);
    na.z = (u32)f2bf(a1.x*scA) | ((u32)f2bf(a1.y*scA)<<16);
    na.w = (u32)f2bf(a1.z*scA) | ((u32)f2bf(a1.w*scA)<<16);
    nb.x = (u32)f2bf(b0.x*scB) | ((u32)f2bf(b0.y*scB)<<16);
    nb.y = (u32)f2bf(b0.z*scB) | ((u32)f2bf(b0.w*scB)<<16);
    nb.z = (u32)f2bf(b1.x*scB) | ((u32)f2bf(b1.y*scB)<<16);
    nb.w = (u32)f2bf(b1.z*scB) | ((u32)f2bf(b1.w*scB)<<16);
    *(uint4*)(entnbf + (size_t)eA*64 + l16*4) = na;
    *(uint4*)(entnbf + (size_t)eB*64 + l16*4) = nb;
  }
}

// ------- K2b: BN0 stats from L3-hot entnbf; partials to pstat (no atomics) --
__global__ __launch_bounds__(256) void k_stats(const u32* __restrict__ entnbf,
    const int* __restrict__ cnt0, const int* __restrict__ cnt1,
    float* __restrict__ pstat){
  __shared__ float acc[512];
  int t = threadIdx.x;
  acc[t] = 0.f; acc[t+256] = 0.f;
  __syncthreads();
  int lane = t & 63;
  int l16 = lane & 15, g = lane >> 4;
  int wid = blockIdx.x*4 + (t>>6), nw = gridDim.x*4;
  float s0[8]={0,0,0,0,0,0,0,0}, s1[8]={0,0,0,0,0,0,0,0};
  float q0[8]={0,0,0,0,0,0,0,0}, q1[8]={0,0,0,0,0,0,0,0};
  for(int e4 = wid*4; e4 < N_ENT; e4 += nw*4){
    int e = e4 + g;
    uint4 u = *(const uint4*)(entnbf + (size_t)e*64 + l16*4);
    float w0 = (float)cnt0[e], w1 = (float)cnt1[e];
    float v[8] = {bfl(u.x),bfh(u.x),bfl(u.y),bfh(u.y),
                  bfl(u.z),bfh(u.z),bfl(u.w),bfh(u.w)};
    #pragma unroll
    for(int k=0;k<8;k++){
      s0[k] += w0*v[k]; s1[k] += w1*v[k];
      q0[k] += w0*v[k]*v[k]; q1[k] += w1*v[k]*v[k];
    }
  }
  #pragma unroll
  for(int k=0;k<8;k++){
    int c = l16*8 + k;
    atomicAdd(&acc[c],     s0[k]);
    atomicAdd(&acc[128+c], s1[k]);
    atomicAdd(&acc[256+c], q0[k]);
    atomicAdd(&acc[384+c], q1[k]);
  }
  __syncthreads();
  pstat[(size_t)blockIdx.x*512 + t]       = acc[t];
  pstat[(size_t)blockIdx.x*512 + 256 + t] = acc[t+256];
}

// ------- K2c: reduce stat partials into stats[0..512): 64 blocks ------------
__global__ __launch_bounds__(256) void k_redstats(const float* __restrict__ pstat,
    float* __restrict__ stats){
  int tid = blockIdx.x*256 + threadIdx.x;     // 64*256 = 16384 threads
  int c = tid & 511;
  int chunk = tid >> 9;                       // 0..31
  float s = 0.f;
  #pragma unroll 4
  for(int k=0;k<STAT_BLKS/32;k++)
    s += pstat[(size_t)(chunk*(STAT_BLKS/32) + k)*512 + c];
  atomicAdd(&stats[c], s);
}

// ------- K3: per-rel scale + Qr stats (LDS-aggregated) + phase tables -------
__global__ __launch_bounds__(256) void k_relstats(const float* __restrict__ rel,
    const int* __restrict__ cntr, float* __restrict__ scale_rel,
    float* __restrict__ stats, float* __restrict__ cosr, float* __restrict__ sinr){
  __shared__ float qacc[128];
  int t = threadIdx.x, lane = t & 63;
  if(t < 128) qacc[t] = 0.f;
  __syncthreads();
  int r = blockIdx.x*4 + (t>>6);
  if(r < N_REL){
    float2 x = *(const float2*)(rel + (size_t)r*D + 2*lane);
    float ss = x.x*x.x + x.y*x.y;
    #pragma unroll
    for(int o=32;o>0;o>>=1) ss += __shfl_xor(ss,o,64);
    float nrm = sqrtf(ss);
    float sc = nrm > 1.0f ? 1.0f/nrm : 1.0f;
    if(lane==0) scale_rel[r] = sc;
    float w = (float)cntr[r];
    float sx = x.x*sc, sy = x.y*sc;
    atomicAdd(&qacc[2*lane  ], w*sx*sx);
    atomicAdd(&qacc[2*lane+1], w*sy*sy);
    if(lane < 32){
      cosr[r*64 + 2*lane  ] = cosf(x.x*PHASE_C);
      sinr[r*64 + 2*lane  ] = sinf(x.x*PHASE_C);
      cosr[r*64 + 2*lane+1] = cosf(x.y*PHASE_C);
      sinr[r*64 + 2*lane+1] = sinf(x.y*PHASE_C);
    }
  }
  __syncthreads();
  if(t < 128) atomicAdd(&stats[512+t], qacc[t]);
}

// ------- K4: finalize BN0, build folded bf16 weights Wbf, W2 and b' ---------
__global__ __launch_bounds__(384) void k_bn0fin(const float* __restrict__ stats,
    const float* __restrict__ W_a, const float* __restrict__ b_a,
    const float* __restrict__ gamma0, const float* __restrict__ beta0,
    u16* __restrict__ Wbf, float* __restrict__ W2, float* __restrict__ bprime){
  __shared__ float a0[384], c0[384];
  int t = threadIdx.x;
  {
    int j = t & 127;
    float mu, ex2;
    if(t < 256){
      mu  = (stats[j]     + stats[128+j]) * (1.0f/(2.0f*N_TRIP));
      ex2 = (stats[256+j] + stats[384+j]) * (1.0f/(2.0f*N_TRIP));
    } else {
      mu  = 0.0f;
      ex2 = stats[512+j] * (1.0f/N_TRIP);
    }
    float var = ex2 - mu*mu;
    float a = gamma0[t]*rsqrtf(var + BN_EPSF);
    a0[t] = a;
    c0[t] = beta0[t] - mu*a;
  }
  __syncthreads();
  for(int idx=t; idx<256*128; idx+=384){
    int j = idx>>7, k = idx&127;
    int ko = ((j>>7)<<7) + k;
    Wbf[idx] = f2bf(W_a[(j&127)*384 + ko]*a0[ko]);
  }
  for(int idx=t; idx<128*128; idx+=384){
    int k = idx>>7, j = idx&127;
    W2[idx] = W_a[j*384 + 256 + k]*a0[256+k];
  }
  if(t < 128){
    float s = b_a[t];
    for(int k=0;k<384;k++) s += W_a[t*384+k]*c0[k];
    bprime[t] = s;
  }
}

// ------- K5: R[r] = rel_n[r] @ W2 ------------------------------------------
__global__ __launch_bounds__(128) void k_relproj(const float* __restrict__ rel,
    const float* __restrict__ scale_rel, const float* __restrict__ W2,
    float* __restrict__ R){
  int r = blockIdx.x, j = threadIdx.x;
  __shared__ float x[128];
  x[j] = rel[(size_t)r*D + j]*scale_rel[r];
  __syncthreads();
  float s = 0.f;
  for(int k=0;k<128;k++) s += x[k]*W2[k*128+j];
  R[r*128+j] = s;
}

// ------- K6: A/B projection via MFMA; input is pre-normalized bf16 ----------
__global__ __launch_bounds__(256) void k_ab(const u32* __restrict__ entnbf,
    const u16* __restrict__ Wbf, u16* __restrict__ Abuf, u16* __restrict__ Bbuf){
  __shared__ u16 xlds[16*128];
  int t = threadIdx.x, lane = t & 63, q = t >> 6;
  int kgrp = (lane>>4)<<3;
  int rgrp = (lane>>4)<<2;
  int frow = lane & 15;
  short8 wf[4][4];
  #pragma unroll
  for(int jt=0;jt<4;jt++){
    #pragma unroll
    for(int kt=0;kt<4;kt++)
      wf[jt][kt] = *(const short8*)(Wbf + (size_t)(q*64 + jt*16 + frow)*D + kgrp + kt*32);
  }
  int srow = t>>4;
  int scol16 = t&15;
  char* swp = (char*)xlds + srow*256 + ((scol16<<4) ^ ((srow&7)<<4));
  const char* rdp = (const char*)xlds + frow*256;
  int rbase0 = (lane>>4)<<4;
  int fsw = (frow&7)<<4;
  for(int chunk = blockIdx.x; chunk < N_ENT/16; chunk += gridDim.x){
    uint4 pk = *(const uint4*)(entnbf + (size_t)(chunk*16 + srow)*64 + scol16*4);
    __syncthreads();
    *(uint4*)swp = pk;
    __syncthreads();
    short8 xf[4];
    #pragma unroll
    for(int kt=0;kt<4;kt++)
      xf[kt] = *(const short8*)(rdp + ((rbase0 + kt*64) ^ fsw));
    int erow = chunk*16 + frow;
    #pragma unroll
    for(int jt=0;jt<4;jt++){
      f32x4 acc = {0.f,0.f,0.f,0.f};
      #pragma unroll
      for(int kt=0;kt<4;kt++)
        acc = __builtin_amdgcn_mfma_f32_16x16x32_bf16(wf[jt][kt], xf[kt], acc, 0,0,0);
      int jbase = q*64 + jt*16 + rgrp;
      u16x4 opk;
      opk.x=f2bf(acc[0]); opk.y=f2bf(acc[1]); opk.z=f2bf(acc[2]); opk.w=f2bf(acc[3]);
      u16* dst = (jbase < 128) ? (Abuf + (size_t)erow*D + jbase)
                               : (Bbuf + (size_t)erow*D + (jbase-128));
      *(u16x4*)dst = opk;
    }
  }
}

// ------- K7: BN1 stats, 1/4 subsample, partials to scratch (no atomics) -----
__global__ __launch_bounds__(256) void k_bn1stats(const u64* __restrict__ pair64,
    const u16* __restrict__ A, const u16* __restrict__ B,
    const float* __restrict__ R, const float* __restrict__ bprime,
    float* __restrict__ pstat1){
  __shared__ float acc[256];
  int t = threadIdx.x;
  acc[t] = 0.f;
  __syncthreads();
  int lane = t & 63;
  int gw = blockIdx.x*4 + (t>>6), nw = gridDim.x*4;
  float bp0 = bprime[2*lane], bp1 = bprime[2*lane+1];
  float s0=0,s1=0,q0=0,q1=0;
  for(int i=4*gw; i<N_TRIP; i+=8*nw){
    {
      u64 pr = pair64[i];
      int t0 = (int)(pr & 0x3FFFF);
      int t1 = (int)((pr>>18) & 0x3FFFF);
      int t2 = (int)(pr>>36);
      u32 ua0 = *(const u32*)(A + (size_t)t0*D + 2*lane);
      u32 ua1 = *(const u32*)(A + (size_t)t1*D + 2*lane);
      u32 ub0 = *(const u32*)(B + (size_t)t0*D + 2*lane);
      u32 ub1 = *(const u32*)(B + (size_t)t1*D + 2*lane);
      float2 r = *(const float2*)(R + (size_t)t2*D + 2*lane);
      float y1x = bfl(ua0)+bfl(ub1)+r.x+bp0;
      float y1y = bfh(ua0)+bfh(ub1)+r.y+bp1;
      float y2x = bfl(ua1)+bfl(ub0)-r.x+bp0;
      float y2y = bfh(ua1)+bfh(ub0)-r.y+bp1;
      s0 += y1x+y2x; s1 += y1y+y2y;
      q0 += y1x*y1x + y2x*y2x; q1 += y1y*y1y + y2y*y2y;
    }
    int i2 = i + 4*nw;
    if(i2 < N_TRIP){
      u64 pr = pair64[i2];
      int t0 = (int)(pr & 0x3FFFF);
      int t1 = (int)((pr>>18) & 0x3FFFF);
      int t2 = (int)(pr>>36);
      u32 ua0 = *(const u32*)(A + (size_t)t0*D + 2*lane);
      u32 ua1 = *(const u32*)(A + (size_t)t1*D + 2*lane);
      u32 ub0 = *(const u32*)(B + (size_t)t0*D + 2*lane);
      u32 ub1 = *(const u32*)(B + (size_t)t1*D + 2*lane);
      float2 r = *(const float2*)(R + (size_t)t2*D + 2*lane);
      float y1x = bfl(ua0)+bfl(ub1)+r.x+bp0;
      float y1y = bfh(ua0)+bfh(ub1)+r.y+bp1;
      float y2x = bfl(ua1)+bfl(ub0)-r.x+bp0;
      float y2y = bfh(ua1)+bfh(ub0)-r.y+bp1;
      s0 += y1x+y2x; s1 += y1y+y2y;
      q0 += y1x*y1x + y2x*y2x; q1 += y1y*y1y + y2y*y2y;
    }
  }
  atomicAdd(&acc[      2*lane  ], s0);
  atomicAdd(&acc[      2*lane+1], s1);
  atomicAdd(&acc[128 + 2*lane  ], q0);
  atomicAdd(&acc[128 + 2*lane+1], q1);
  __syncthreads();
  pstat1[(size_t)blockIdx.x*256 + t] = acc[t];
}

// ------- K8: reduce BN1 partials + finalize + u-vectors ---------------------
// a1c layout: [0:128)=a1 [128:256)=cc [256:384)=wa1 [384]=kap
//             [512:640)=uA = W'_A^T wa1   [640:768)=uB = W'_B^T wa1
__global__ __launch_bounds__(128) void k_bn1fin(const float* __restrict__ pstat1,
    const float* __restrict__ gamma1, const float* __restrict__ beta1,
    const float* __restrict__ W_a2, const float* __restrict__ b_a2,
    const float* __restrict__ bprime, const u16* __restrict__ Wbf,
    float* __restrict__ a1c){
  __shared__ float red[128];
  __shared__ float swa1[128];
  int j = threadIdx.x;
  float s = 0.f, q = 0.f;
  for(int b=0;b<BN1_BLKS;b++){
    s += pstat1[(size_t)b*256 + j];
    q += pstat1[(size_t)b*256 + 128 + j];
  }
  float mu  = s*(2.0f/(float)N_TRIP);
  float var = q*(2.0f/(float)N_TRIP) - mu*mu;
  float a = gamma1[j]*rsqrtf(var + BN_EPSF);
  float cc = beta1[j] - mu*a;
  float wa1 = W_a2[j]*a;
  a1c[j]     = a;
  a1c[128+j] = cc;
  a1c[256+j] = wa1;
  swa1[j] = wa1;
  red[j] = W_a2[j]*cc + wa1*bprime[j];
  __syncthreads();
  float uA = 0.f, uB = 0.f;
  for(int jj=0; jj<128; jj++){
    float w = swa1[jj];
    uA += w*bfu(Wbf[jj*D + j]);
    uB += w*bfu(Wbf[(128+jj)*D + j]);
  }
  a1c[512+j] = uA;
  a1c[640+j] = uB;
  #pragma unroll
  for(int st=64; st>0; st>>=1){
    if(j < st) red[j] += red[j+st];
    __syncthreads();
  }
  if(j==0) a1c[384] = red[0] + b_a2[0];
}

// ------- K8b: per-entity scalars from entnbf via u-vectors (half traffic) ---
__global__ __launch_bounds__(256) void k_alphabeta(const u32* __restrict__ entnbf,
    const float* __restrict__ R, const float* __restrict__ a1c,
    float* __restrict__ alpha, float* __restrict__ beta, float* __restrict__ rho){
  int t = threadIdx.x, lane = t & 63;
  int l16 = lane & 15, g = lane >> 4;
  int wid = blockIdx.x*4 + (t>>6), nw = gridDim.x*4;
  int cb = l16*8;
  float4 uA0 = *(const float4*)(a1c + 512 + cb);
  float4 uA1 = *(const float4*)(a1c + 512 + cb + 4);
  float4 uB0 = *(const float4*)(a1c + 640 + cb);
  float4 uB1 = *(const float4*)(a1c + 640 + cb + 4);
  for(int e4 = wid*4; e4 < N_ENT; e4 += nw*4){
    int e = e4 + g;
    uint4 u = *(const uint4*)(entnbf + (size_t)e*64 + l16*4);
    float v0=bfl(u.x), v1=bfh(u.x), v2=bfl(u.y), v3=bfh(u.y);
    float v4=bfl(u.z), v5=bfh(u.z), v6=bfl(u.w), v7=bfh(u.w);
    float da = v0*uA0.x + v1*uA0.y + v2*uA0.z + v3*uA0.w
             + v4*uA1.x + v5*uA1.y + v6*uA1.z + v7*uA1.w;
    float db = v0*uB0.x + v1*uB0.y + v2*uB0.z + v3*uB0.w
             + v4*uB1.x + v5*uB1.y + v6*uB1.z + v7*uB1.w;
    #pragma unroll
    for(int o=8;o>0;o>>=1){
      da += __shfl_xor(da,o,64);
      db += __shfl_xor(db,o,64);
    }
    if(l16==0){ alpha[e]=da; beta[e]=db; }
  }
  float4 w0 = *(const float4*)(a1c + 256 + cb);
  float4 w1 = *(const float4*)(a1c + 256 + cb + 4);
  for(int r4 = wid*4; r4 < N_REL; r4 += nw*4){
    int r = r4 + g;
    if(r < N_REL){
      float4 rA = *(const float4*)(R + (size_t)r*D + cb);
      float4 rB = *(const float4*)(R + (size_t)r*D + cb + 4);
      float dr = rA.x*w0.x + rA.y*w0.y + rA.z*w0.z + rA.w*w0.w
               + rB.x*w1.x + rB.y*w1.y + rB.z*w1.z + rB.w*w1.w;
      #pragma unroll
      for(int o=8;o>0;o>>=1) dr += __shfl_xor(dr,o,64);
      if(l16==0) rho[r]=dr;
    }
  }
}

// ------- K9: per-entity gather, 16-lane groups, x2 edge unroll --------------
__global__ __launch_bounds__(256) void k_ent(
    const int* __restrict__ offs, const int* __restrict__ endp,
    const u32* __restrict__ ebuf,
    const u16* __restrict__ A, const u16* __restrict__ B,
    const float* __restrict__ R, const float* __restrict__ bprime,
    const float* __restrict__ a1c, const float* __restrict__ alpha,
    const float* __restrict__ beta, const float* __restrict__ rho,
    float* __restrict__ out_hent){
  int t = threadIdx.x, lane = t & 63;
  int l16 = lane & 15, g = lane >> 4;
  int wid = blockIdx.x*4 + (t>>6), nw = gridDim.x*4;
  int cb = l16*8;
  float4 bpA = *(const float4*)(bprime + cb);
  float4 bpB = *(const float4*)(bprime + cb + 4);
  float4 a1A = *(const float4*)(a1c + cb);
  float4 a1B = *(const float4*)(a1c + cb + 4);
  float4 ccA = *(const float4*)(a1c + 128 + cb);
  float4 ccB = *(const float4*)(a1c + 128 + cb + 4);
  float kap = a1c[384];
  for(int e4 = wid*4; e4 < N_ENT; e4 += nw*4){
    int e = e4 + g;
    int s = offs[e], en = endp[e];
    uint4 ua = *(const uint4*)(A + (size_t)e*D + cb);
    float ax0 = bfl(ua.x), ax1 = bfh(ua.x), ax2 = bfl(ua.y), ax3 = bfh(ua.y);
    float ax4 = bfl(ua.z), ax5 = bfh(ua.z), ax6 = bfl(ua.w), ax7 = bfh(ua.w);
    float al = alpha[e];
    float h0=0,h1=0,h2=0,h3=0,h4=0,h5=0,h6=0,h7=0, eb=0;
    int o = s;
    for(; o+1<en; o+=2){
      u32 idX = ebuf[o], idY = ebuf[o+1];
      int otX = idX>>10, r2X = (idX>>1)&511;
      int otY = idY>>10, r2Y = (idY>>1)&511;
      float sgX = (idX&1) ? -1.f : 1.f;
      float sgY = (idY&1) ? -1.f : 1.f;
      uint4 ubX = *(const uint4*)(B + (size_t)otX*D + cb);
      uint4 ubY = *(const uint4*)(B + (size_t)otY*D + cb);
      float4 rAX = *(const float4*)(R + (size_t)r2X*D + cb);
      float4 rBX = *(const float4*)(R + (size_t)r2X*D + cb + 4);
      float4 rAY = *(const float4*)(R + (size_t)r2Y*D + cb);
      float4 rBY = *(const float4*)(R + (size_t)r2Y*D + cb + 4);
      float beX = beta[otX], beY = beta[otY];
      float roX = rho[r2X],  roY = rho[r2Y];
      float svX = al + beX + sgX*roX + kap;
      float svY = al + beY + sgY*roY + kap;
      float ebX = expf(svX >= 0.f ? -svX : -0.01f*svX);
      float ebY = expf(svY >= 0.f ? -svY : -0.01f*svY);
      float y, c;
      y = ax0 + bfl(ubX.x) + sgX*rAX.x + bpA.x; c = y*a1A.x + ccA.x; h0 += ebX*c;
      y = ax1 + bfh(ubX.x) + sgX*rAX.y + bpA.y; c = y*a1A.y + ccA.y; h1 += ebX*c;
      y = ax2 + bfl(ubX.y) + sgX*rAX.z + bpA.z; c = y*a1A.z + ccA.z; h2 += ebX*c;
      y = ax3 + bfh(ubX.y) + sgX*rAX.w + bpA.w; c = y*a1A.w + ccA.w; h3 += ebX*c;
      y = ax4 + bfl(ubX.z) + sgX*rBX.x + bpB.x; c = y*a1B.x + ccB.x; h4 += ebX*c;
      y = ax5 + bfh(ubX.z) + sgX*rBX.y + bpB.y; c = y*a1B.y + ccB.y; h5 += ebX*c;
      y = ax6 + bfl(ubX.w) + sgX*rBX.z + bpB.z; c = y*a1B.z + ccB.z; h6 += ebX*c;
      y = ax7 + bfh(ubX.w) + sgX*rBX.w + bpB.w; c = y*a1B.w + ccB.w; h7 += ebX*c;
      y = ax0 + bfl(ubY.x) + sgY*rAY.x + bpA.x; c = y*a1A.x + ccA.x; h0 += ebY*c;
      y = ax1 + bfh(ubY.x) + sgY*rAY.y + bpA.y; c = y*a1A.y + ccA.y; h1 += ebY*c;
      y = ax2 + bfl(ubY.y) + sgY*rAY.z + bpA.z; c = y*a1A.z + ccA.z; h2 += ebY*c;
      y = ax3 + bfh(ubY.y) + sgY*rAY.w + bpA.w; c = y*a1A.w + ccA.w; h3 += ebY*c;
      y = ax4 + bfl(ubY.z) + sgY*rBY.x + bpB.x; c = y*a1B.x + ccB.x; h4 += ebY*c;
      y = ax5 + bfh(ubY.z) + sgY*rBY.y + bpB.y; c = y*a1B.y + ccB.y; h5 += ebY*c;
      y = ax6 + bfl(ubY.w) + sgY*rBY.z + bpB.z; c = y*a1B.z + ccB.z; h6 += ebY*c;
      y = ax7 + bfh(ubY.w) + sgY*rBY.w + bpB.w; c = y*a1B.w + ccB.w; h7 += ebY*c;
      eb += ebX + ebY;
    }
    if(o < en){
      u32 id = ebuf[o];
      int ot = id>>10, r2 = (id>>1)&511;
      float sg = (id&1) ? -1.f : 1.f;
      uint4 ub = *(const uint4*)(B + (size_t)ot*D + cb);
      float4 rA = *(const float4*)(R + (size_t)r2*D + cb);
      float4 rB = *(const float4*)(R + (size_t)r2*D + cb + 4);
      float sv = al + beta[ot] + sg*rho[r2] + kap;
      float e_b = expf(sv >= 0.f ? -sv : -0.01f*sv);
      float y, c;
      y = ax0 + bfl(ub.x) + sg*rA.x + bpA.x; c = y*a1A.x + ccA.x; h0 += e_b*c;
      y = ax1 + bfh(ub.x) + sg*rA.y + bpA.y; c = y*a1A.y + ccA.y; h1 += e_b*c;
      y = ax2 + bfl(ub.y) + sg*rA.z + bpA.z; c = y*a1A.z + ccA.z; h2 += e_b*c;
      y = ax3 + bfh(ub.y) + sg*rA.w + bpA.w; c = y*a1A.w + ccA.w; h3 += e_b*c;
      y = ax4 + bfl(ub.z) + sg*rB.x + bpB.x; c = y*a1B.x + ccB.x; h4 += e_b*c;
      y = ax5 + bfh(ub.z) + sg*rB.y + bpB.y; c = y*a1B.y + ccB.y; h5 += e_b*c;
      y = ax6 + bfl(ub.w) + sg*rB.z + bpB.z; c = y*a1B.z + ccB.z; h6 += e_b*c;
      y = ax7 + bfh(ub.w) + sg*rB.w + bpB.w; c = y*a1B.w + ccB.w; h7 += e_b*c;
      eb += e_b;
    }
    float inv = (en > s) ? 1.0f/eb : 0.0f;
    float4 o0; o0.x=h0*inv; o0.y=h1*inv; o0.z=h2*inv; o0.w=h3*inv;
    float4 o1; o1.x=h4*inv; o1.y=h5*inv; o1.z=h6*inv; o1.w=h7*inv;
    *(float4*)(out_hent + (size_t)e*D + cb)     = o0;
    *(float4*)(out_hent + (size_t)e*D + cb + 4) = o1;
  }
}

// ------- K10: per-rel gather pass, packed pairs, x2 unrolled ----------------
__global__ __launch_bounds__(512) void k_rel(
    const int* __restrict__ roffs, const int* __restrict__ cntr,
    const u64* __restrict__ rpair,
    const u16* __restrict__ A, const u16* __restrict__ B,
    const float* __restrict__ R, const float* __restrict__ bprime,
    const float* __restrict__ a1c, const float* __restrict__ alpha,
    const float* __restrict__ beta, const float* __restrict__ rho,
    float* __restrict__ out_hrel){
  __shared__ float red[8][128];
  int t = threadIdx.x, lane = t & 63, w = t >> 6;
  int r = blockIdx.x;
  int cnt = cntr[r], base = roffs[r];
  float2 rr = *(const float2*)(R + (size_t)r*D + 2*lane);
  float bp0 = bprime[2*lane], bp1 = bprime[2*lane+1];
  float a1x = a1c[2*lane],     a1y = a1c[2*lane+1];
  float ccx = a1c[128+2*lane], ccy = a1c[128+2*lane+1];
  float kap = a1c[384];
  float rhor = rho[r];
  float sx = 0.f, sy = 0.f;
  for(int j=w; j<cnt; j+=16){
    {
      u64 pr = rpair[base+j];
      int t0 = (int)(pr & 0x3FFFF);
      int t1 = (int)((pr>>18) & 0x3FFFF);
      float s1 = alpha[t0] + beta[t1] + rhor + kap;
      float s2 = alpha[t1] + beta[t0] - rhor + kap;
      float e1 = expf(s1 >= 0.f ? -s1 : -0.01f*s1);
      float e2 = expf(s2 >= 0.f ? -s2 : -0.01f*s2);
      u32 ua0 = *(const u32*)(A + (size_t)t0*D + 2*lane);
      u32 ua1 = *(const u32*)(A + (size_t)t1*D + 2*lane);
      u32 ub0 = *(const u32*)(B + (size_t)t0*D + 2*lane);
      u32 ub1 = *(const u32*)(B + (size_t)t1*D + 2*lane);
      float y1x = bfl(ua0)+bfl(ub1)+rr.x+bp0;
      float y1y = bfh(ua0)+bfh(ub1)+rr.y+bp1;
      float y2x = bfl(ua1)+bfl(ub0)-rr.x+bp0;
      float y2y = bfh(ua1)+bfh(ub0)-rr.y+bp1;
      float c1x = y1x*a1x+ccx, c1y = y1y*a1y+ccy;
      float c2x = y2x*a1x+ccx, c2y = y2y*a1y+ccy;
      sx += e1*c1x - e2*c2x;
      sy += e1*c1y - e2*c2y;
    }
    int j2 = j + 8;
    if(j2 < cnt){
      u64 pr = rpair[base+j2];
      int t0 = (int)(pr & 0x3FFFF);
      int t1 = (int)((pr>>18) & 0x3FFFF);
      float s1 = alpha[t0] + beta[t1] + rhor + kap;
      float s2 = alpha[t1] + beta[t0] - rhor + kap;
      float e1 = expf(s1 >= 0.f ? -s1 : -0.01f*s1);
      float e2 = expf(s2 >= 0.f ? -s2 : -0.01f*s2);
      u32 ua0 = *(const u32*)(A + (size_t)t0*D + 2*lane);
      u32 ua1 = *(const u32*)(A + (size_t)t1*D + 2*lane);
      u32 ub0 = *(const u32*)(B + (size_t)t0*D + 2*lane);
      u32 ub1 = *(const u32*)(B + (size_t)t1*D + 2*lane);
      float y1x = bfl(ua0)+bfl(ub1)+rr.x+bp0;
      float y1y = bfh(ua0)+bfh(ub1)+rr.y+bp1;
      float y2x = bfl(ua1)+bfl(ub0)-rr.x+bp0;
      float y2y = bfh(ua1)+bfh(ub0)-rr.y+bp1;
      float c1x = y1x*a1x+ccx, c1y = y1y*a1y+ccy;
      float c2x = y2x*a1x+ccx, c2y = y2y*a1y+ccy;
      sx += e1*c1x - e2*c2x;
      sy += e1*c1y - e2*c2y;
    }
  }
  float2 p; p.x = sx; p.y = sy;
  *(float2*)&red[w][2*lane] = p;
  __syncthreads();
  if(t < 128){
    float s = 0.f;
    #pragma unroll
    for(int k=0;k<8;k++) s += red[k][t];
    float cf = cnt > 0 ? (float)cnt : 1.0f;
    out_hrel[(size_t)r*D + t] = s/cf;
  }
}

// ------- K12: RotatE score, bf16 gathers, 16-lane groups --------------------
__global__ __launch_bounds__(256) void k_score_bf(const u64* __restrict__ pair64,
    const u32* __restrict__ entbf, const float* __restrict__ cosr,
    const float* __restrict__ sinr, float* __restrict__ score){
  int t = threadIdx.x, lane = t & 63;
  int l16 = lane & 15, g = lane >> 4;
  int wid = blockIdx.x*4 + (t>>6), nw = gridDim.x*4;
  for(int i4 = wid*4; i4 < N_TRIP; i4 += nw*4){
    int i = i4 + g;
    u64 pr = pair64[i];
    int t0 = (int)(pr & 0x3FFFF);
    int t1 = (int)((pr>>18) & 0x3FFFF);
    int t2 = (int)(pr>>36);
    uint2 reh = *(const uint2*)(entbf + (size_t)t0*64 + l16*2);
    uint2 imh = *(const uint2*)(entbf + (size_t)t0*64 + 32 + l16*2);
    uint2 ret = *(const uint2*)(entbf + (size_t)t1*64 + l16*2);
    uint2 imt = *(const uint2*)(entbf + (size_t)t1*64 + 32 + l16*2);
    float4 cr = *(const float4*)(cosr + (size_t)t2*64 + l16*4);
    float4 sr = *(const float4*)(sinr + (size_t)t2*64 + l16*4);
    float rh[4] = {bfl(reh.x),bfh(reh.x),bfl(reh.y),bfh(reh.y)};
    float ih[4] = {bfl(imh.x),bfh(imh.x),bfl(imh.y),bfh(imh.y)};
    float rt[4] = {bfl(ret.x),bfh(ret.x),bfl(ret.y),bfh(ret.y)};
    float it[4] = {bfl(imt.x),bfh(imt.x),bfl(imt.y),bfh(imt.y)};
    float cc[4] = {cr.x,cr.y,cr.z,cr.w};
    float ss[4] = {sr.x,sr.y,sr.z,sr.w};
    float d = 0.f;
    #pragma unroll
    for(int k=0;k<4;k++){
      float res = cc[k]*rt[k] + ss[k]*it[k] - rh[k];
      float ims = cc[k]*it[k] - ss[k]*rt[k] - ih[k];
      d += sqrtf(res*res + ims*ims);
    }
    #pragma unroll
    for(int o=8;o>0;o>>=1) d += __shfl_xor(d,o,64);
    if(l16==0) score[i] = MARGINF - d;
  }
}

// fp32 fallback if workspace too small for entbf
__global__ __launch_bounds__(256) void k_score_fp(const u64* __restrict__ pair64,
    const float* __restrict__ ent, const float* __restrict__ cosr,
    const float* __restrict__ sinr, float* __restrict__ score){
  int t = threadIdx.x, lane = t & 63;
  int l16 = lane & 15, g = lane >> 4;
  int wid = blockIdx.x*4 + (t>>6), nw = gridDim.x*4;
  for(int i4 = wid*4; i4 < N_TRIP; i4 += nw*4){
    int i = i4 + g;
    u64 pr = pair64[i];
    int t0 = (int)(pr & 0x3FFFF);
    int t1 = (int)((pr>>18) & 0x3FFFF);
    int t2 = (int)(pr>>36);
    float4 rh = *(const float4*)(ent + (size_t)t0*D + l16*4);
    float4 ih = *(const float4*)(ent + (size_t)t0*D + 64 + l16*4);
    float4 rt = *(const float4*)(ent + (size_t)t1*D + l16*4);
    float4 it = *(const float4*)(ent + (size_t)t1*D + 64 + l16*4);
    float4 cr = *(const float4*)(cosr + (size_t)t2*64 + l16*4);
    float4 sr = *(const float4*)(sinr + (size_t)t2*64 + l16*4);
    float rha[4] = {rh.x,rh.y,rh.z,rh.w};
    float iha[4] = {ih.x,ih.y,ih.z,ih.w};
    float rta[4] = {rt.x,rt.y,rt.z,rt.w};
    float ita[4] = {it.x,it.y,it.z,it.w};
    float cca[4] = {cr.x,cr.y,cr.z,cr.w};
    float ssa[4] = {sr.x,sr.y,sr.z,sr.w};
    float d = 0.f;
    #pragma unroll
    for(int k=0;k<4;k++){
      float res = cca[k]*rta[k] + ssa[k]*ita[k] - rha[k];
      float ims = cca[k]*ita[k] - ssa[k]*rta[k] - iha[k];
      d += sqrtf(res*res + ims*ims);
    }
    #pragma unroll
    for(int o=8;o>0;o>>=1) d += __shfl_xor(d,o,64);
    if(l16==0) score[i] = MARGINF - d;
  }
}

extern "C" void kernel_launch(void* const* d_in, const int* in_sizes, int n_in,
                              void* d_out, int out_size, void* d_ws, size_t ws_size,
                              hipStream_t stream){
  const int*   trip   = (const int*)  d_in[0];
  const float* ent    = (const float*)d_in[1];
  const float* rel    = (const float*)d_in[2];
  const float* W_a    = (const float*)d_in[3];
  const float* b_a    = (const float*)d_in[4];
  const float* W_a2   = (const float*)d_in[5];
  const float* b_a2   = (const float*)d_in[6];
  const float* gamma0 = (const float*)d_in[7];
  const float* beta0  = (const float*)d_in[8];
  const float* gamma1 = (const float*)d_in[9];
  const float* beta1  = (const float*)d_in[10];

  char* ws = (char*)d_ws;
  size_t off = 0;
  auto take = [&](size_t bytes)->void*{
    void* p = ws + off;
    off += (bytes + 255) & ~(size_t)255;
    return p;
  };
  // ---- zeroed scratch (contiguous from 0) ----
  int*   cnt0    = (int*)  take((size_t)N_ENT*4);
  int*   cnt1    = (int*)  take((size_t)N_ENT*4);
  int*   cntr    = (int*)  take((size_t)N_REL*4);
  float* stats   = (float*)take(640*4);
  size_t zero_bytes = off;
  // ---- fully-overwritten scratch ----
  int*   offs      = (int*)  take((size_t)N_ENT*4);
  int*   cur       = (int*)  take((size_t)N_ENT*4);
  int*   bsum      = (int*)  take(512*4);
  int*   boffs     = (int*)  take(512*4);
  int*   roffs     = (int*)  take(512*4);
  int*   rcur      = (int*)  take(512*4);
  u32*   ebuf      = (u32*)  take((size_t)2*N_TRIP*4);
  u64*   pair64    = (u64*)  take((size_t)N_TRIP*8);
  u64*   rpair     = (u64*)  take((size_t)N_TRIP*8);
  float* scale_rel = (float*)take((size_t)N_REL*4);
  u16*   Wbf       = (u16*)  take(256*128*2);
  float* W2        = (float*)take(128*128*4);
  float* bprime    = (float*)take(128*4);
  float* a1c       = (float*)take(768*4);
  float* R         = (float*)take((size_t)N_REL*D*4);
  float* cosr      = (float*)take((size_t)N_REL*64*4);
  float* sinr      = (float*)take((size_t)N_REL*64*4);
  float* alpha     = (float*)take((size_t)N_ENT*4);
  float* betab     = (float*)take((size_t)N_ENT*4);
  float* rho       = (float*)take(512*4);
  float* pstat     = (float*)take((size_t)STAT_BLKS*512*4);
  float* pstat1    = (float*)take((size_t)BN1_BLKS*256*4);
  u16*   Abuf      = (u16*)  take((size_t)N_ENT*D*2);
  u16*   Bbuf      = (u16*)  take((size_t)N_ENT*D*2);
  u32*   entnbf    = (u32*)  take((size_t)N_ENT*64*4);
  // ---- optional: raw bf16 copy for k_score ----
  u32*   entbf     = (u32*)  take((size_t)N_ENT*64*4);
  bool use_bf = (off <= ws_size);
  (void)n_in; (void)in_sizes; (void)out_size;

  float* out_hent  = (float*)d_out;
  float* out_hrel  = out_hent + (size_t)N_ENT*D;
  float* out_score = out_hrel + (size_t)N_REL*D;

  hipMemsetAsync(d_ws, 0, zero_bytes, stream);

  const int SCAN_BLKS = (N_ENT + 1023)/1024;     // 196
  const int EDG_BLKS  = (N_TRIP + 2047)/2048;    // 98
  k_hist     <<<EDG_BLKS, 256, 0, stream>>>(trip, cnt0, cnt1, cntr);
  k_prep     <<<2048, 256, 0, stream>>>(ent, entnbf, use_bf ? entbf : (u32*)nullptr);
  k_stats    <<<STAT_BLKS, 256, 0, stream>>>(entnbf, cnt0, cnt1, pstat);
  k_redstats <<<64, 256, 0, stream>>>(pstat, stats);
  k_scan1    <<<SCAN_BLKS, 1024, 0, stream>>>(cnt0, cnt1, offs, bsum);
  k_scan2    <<<1, 512, 0, stream>>>(bsum, boffs, cntr, roffs, rcur, SCAN_BLKS);
  k_scan3    <<<SCAN_BLKS, 1024, 0, stream>>>(offs, boffs, cur);
  k_edges    <<<EDG_BLKS, 256, 0, stream>>>(trip, cur, rcur, ebuf, pair64, rpair);
  k_relstats <<<(N_REL+3)/4, 256, 0, stream>>>(rel, cntr, scale_rel, stats, cosr, sinr);
  k_bn0fin   <<<1, 384, 0, stream>>>(stats, W_a, b_a, gamma0, beta0, Wbf, W2, bprime);
  k_relproj  <<<N_REL, 128, 0, stream>>>(rel, scale_rel, W2, R);
  k_ab       <<<2048, 256, 0, stream>>>(entnbf, Wbf, Abuf, Bbuf);
  k_bn1stats <<<BN1_BLKS, 256, 0, stream>>>(pair64, Abuf, Bbuf, R, bprime, pstat1);
  k_bn1fin   <<<1, 128, 0, stream>>>(pstat1, gamma1, beta1, W_a2, b_a2, bprime, Wbf, a1c);
  k_alphabeta<<<2048, 256, 0, stream>>>(entnbf, R, a1c, alpha, betab, rho);
  k_ent      <<<2048, 256, 0, stream>>>(offs, cur, ebuf, Abuf, Bbuf, R,
                                        bprime, a1c, alpha, betab, rho, out_hent);
  k_rel      <<<N_REL, 512, 0, stream>>>(roffs, cntr, rpair, Abuf, Bbuf, R,
                                         bprime, a1c, alpha, betab, rho, out_hrel);
  if(use_bf)
    k_score_bf<<<2048, 256, 0, stream>>>(pair64, entbf, cosr, sinr, out_score);
  else
    k_score_fp<<<2048, 256, 0, stream>>>(pair64, ent, cosr, sinr, out_score);
}

// Round 16
// 405.367 us; speedup vs baseline: 1.0157x; 1.0157x over previous
//
#include <hip/hip_runtime.h>
#include <stdint.h>

#define N_TRIP 200000
#define N_ENT  200000
#define N_REL  500
#define D      128
#define MARGINF 6.0f
#define BN_EPSF 1e-5f
#define PHASE_C 50.26548245743669f   // PI / REL_RANGE, REL_RANGE = 8/128
#define STAT_BLKS 256
#define BN1_BLKS  240

typedef unsigned short u16;
typedef unsigned int   u32;
typedef unsigned long long u64;
typedef __attribute__((ext_vector_type(8))) short short8;
typedef __attribute__((ext_vector_type(4))) float f32x4;
typedef __attribute__((ext_vector_type(4))) unsigned short u16x4;

__device__ inline float bfl(u32 u){ return __uint_as_float(u<<16); }
__device__ inline float bfh(u32 u){ return __uint_as_float(u&0xffff0000u); }
__device__ inline float bfu(u16 u){ return __uint_as_float(((u32)u)<<16); }
__device__ inline u16 f2bf(float f){
  u32 u = __float_as_uint(f);
  u32 r = (u + 0x7fffu + ((u>>16)&1u))>>16;
  return (u16)r;
}

// ------- K1: histogram; rel counts aggregated in LDS ------------------------
__global__ __launch_bounds__(256) void k_hist(const int* __restrict__ trip,
    int* __restrict__ cnt0, int* __restrict__ cnt1, int* __restrict__ cntr){
  __shared__ int rc[N_REL];
  int t = threadIdx.x;
  for(int r=t; r<N_REL; r+=256) rc[r]=0;
  __syncthreads();
  #pragma unroll
  for(int k=0;k<8;k++){
    int i = blockIdx.x*2048 + t + k*256;
    if(i < N_TRIP){
      atomicAdd(&cnt0[trip[3*i]],   1);
      atomicAdd(&cnt1[trip[3*i+1]], 1);
      atomicAdd(&rc[trip[3*i+2]],   1);
    }
  }
  __syncthreads();
  for(int r=t; r<N_REL; r+=256){
    int c = rc[r];
    if(c) atomicAdd(&cntr[r], c);
  }
}

// ---------------- CSR build: 3-kernel prefix scan + cursor scatter ----------
__global__ __launch_bounds__(1024) void k_scan1(const int* __restrict__ cnt0,
    const int* __restrict__ cnt1, int* __restrict__ offs, int* __restrict__ bsum){
  __shared__ int sh[1024];
  int t = threadIdx.x;
  int e = blockIdx.x*1024 + t;
  int d = (e < N_ENT) ? cnt0[e] + cnt1[e] : 0;
  sh[t] = d; __syncthreads();
  for(int st=1; st<1024; st<<=1){
    int x = (t>=st) ? sh[t-st] : 0;
    __syncthreads();
    sh[t] += x;
    __syncthreads();
  }
  if(e < N_ENT) offs[e] = sh[t] - d;
  if(t == 1023) bsum[blockIdx.x] = sh[t];
}

__global__ __launch_bounds__(512) void k_scan2(const int* __restrict__ bsum,
    int* __restrict__ boffs, const int* __restrict__ cntr,
    int* __restrict__ roffs, int* __restrict__ rcur, int nblk){
  __shared__ int sh[512];
  int t = threadIdx.x;
  int v = (t < nblk) ? bsum[t] : 0;
  sh[t] = v; __syncthreads();
  for(int st=1; st<512; st<<=1){
    int x = (t>=st) ? sh[t-st] : 0;
    __syncthreads(); sh[t] += x; __syncthreads();
  }
  if(t < nblk) boffs[t] = sh[t] - v;
  __syncthreads();
  int w = (t < N_REL) ? cntr[t] : 0;
  sh[t] = w; __syncthreads();
  for(int st=1; st<512; st<<=1){
    int x = (t>=st) ? sh[t-st] : 0;
    __syncthreads(); sh[t] += x; __syncthreads();
  }
  if(t < N_REL){ roffs[t] = sh[t]-w; rcur[t] = sh[t]-w; }
}

__global__ __launch_bounds__(1024) void k_scan3(int* __restrict__ offs,
    const int* __restrict__ boffs, int* __restrict__ cur){
  int e = blockIdx.x*1024 + threadIdx.x;
  if(e < N_ENT){
    int o = offs[e] + boffs[blockIdx.x];
    offs[e] = o;
    cur[e] = o;
  }
}

// ------- K-edges: chunked scatter; rel cursors via LDS + bulk alloc ---------
__global__ __launch_bounds__(256) void k_edges(const int* __restrict__ trip,
    int* __restrict__ cur, int* __restrict__ rcur,
    u32* __restrict__ ebuf, u64* __restrict__ pair64, u64* __restrict__ rpair){
  __shared__ int rcnt[N_REL];
  __shared__ int rbase[N_REL];
  int t = threadIdx.x;
  for(int r=t; r<N_REL; r+=256) rcnt[r]=0;
  __syncthreads();
  int i0 = blockIdx.x*2048;
  int lt0[8], lt1[8], lt2[8], lp[8];
  #pragma unroll
  for(int k=0;k<8;k++){
    int i = i0 + t + k*256;
    lt2[k] = -1;
    if(i < N_TRIP){
      int t0 = trip[3*i], t1 = trip[3*i+1], t2 = trip[3*i+2];
      lt0[k]=t0; lt1[k]=t1; lt2[k]=t2;
      lp[k] = atomicAdd(&rcnt[t2], 1);
      pair64[i] = ((u64)t2<<36) | ((u64)t1<<18) | (u64)t0;
      ebuf[atomicAdd(&cur[t0], 1)] = ((u32)t1<<10) | ((u32)t2<<1);
      ebuf[atomicAdd(&cur[t1], 1)] = ((u32)t0<<10) | ((u32)t2<<1) | 1u;
    }
  }
  __syncthreads();
  for(int r=t; r<N_REL; r+=256){
    int c = rcnt[r];
    rbase[r] = c ? atomicAdd(&rcur[r], c) : 0;
  }
  __syncthreads();
  #pragma unroll
  for(int k=0;k<8;k++){
    if(lt2[k] >= 0)
      rpair[rbase[lt2[k]] + lp[k]] =
        ((u64)lt2[k]<<36) | ((u64)lt1[k]<<18) | (u64)lt0[k];
  }
}

// ------- K2a: PURE streaming prep: ent -> entnbf (normalized bf16) ----------
__global__ __launch_bounds__(256) void k_prep(const float* __restrict__ ent,
    u32* __restrict__ entnbf){
  int t = threadIdx.x, lane = t & 63;
  int l16 = lane & 15, g = lane >> 4;
  int wid = blockIdx.x*4 + (t>>6), nw = gridDim.x*4;
  for(int e8 = wid*8; e8 < N_ENT; e8 += nw*8){
    int eA = e8 + g, eB = e8 + 4 + g;
    const float* xpA = ent + (size_t)eA*D + l16*8;
    const float* xpB = ent + (size_t)eB*D + l16*8;
    float4 a0 = *(const float4*)xpA;
    float4 a1 = *(const float4*)(xpA+4);
    float4 b0 = *(const float4*)xpB;
    float4 b1 = *(const float4*)(xpB+4);
    float ssA = a0.x*a0.x + a0.y*a0.y + a0.z*a0.z + a0.w*a0.w
              + a1.x*a1.x + a1.y*a1.y + a1.z*a1.z + a1.w*a1.w;
    float ssB = b0.x*b0.x + b0.y*b0.y + b0.z*b0.z + b0.w*b0.w
              + b1.x*b1.x + b1.y*b1.y + b1.z*b1.z + b1.w*b1.w;
    #pragma unroll
    for(int o=8;o>0;o>>=1){
      ssA += __shfl_xor(ssA,o,64);
      ssB += __shfl_xor(ssB,o,64);
    }
    float nA = sqrtf(ssA), nB = sqrtf(ssB);
    float scA = nA > 1.0f ? 1.0f/nA : 1.0f;
    float scB = nB > 1.0f ? 1.0f/nB : 1.0f;
    uint4 na, nb;
    na.x = (u32)f2bf(a0.x*scA) | ((u32)f2bf(a0.y*scA)<<16);
    na.y = (u32)f2bf(a0.z*scA) | ((u32)f2bf(a0.w*scA)<<16);
    na.z = (u32)f2bf(a1.x*scA) | ((u32)f2bf(a1.y*scA)<<16);
    na.w = (u32)f2bf(a1.z*scA) | ((u32)f2bf(a1.w*scA)<<16);
    nb.x = (u32)f2bf(b0.x*scB) | ((u32)f2bf(b0.y*scB)<<16);
    nb.y = (u32)f2bf(b0.z*scB) | ((u32)f2bf(b0.w*scB)<<16);
    nb.z = (u32)f2bf(b1.x*scB) | ((u32)f2bf(b1.y*scB)<<16);
    nb.w = (u32)f2bf(b1.z*scB) | ((u32)f2bf(b1.w*scB)<<16);
    *(uint4*)(entnbf + (size_t)eA*64 + l16*4) = na;
    *(uint4*)(entnbf + (size_t)eB*64 + l16*4) = nb;
  }
}

// ------- K2b: BN0 stats from L3-hot entnbf; partials to pstat (no atomics) --
__global__ __launch_bounds__(256) void k_stats(const u32* __restrict__ entnbf,
    const int* __restrict__ cnt0, const int* __restrict__ cnt1,
    float* __restrict__ pstat){
  __shared__ float acc[512];
  int t = threadIdx.x;
  acc[t] = 0.f; acc[t+256] = 0.f;
  __syncthreads();
  int lane = t & 63;
  int l16 = lane & 15, g = lane >> 4;
  int wid = blockIdx.x*4 + (t>>6), nw = gridDim.x*4;
  float s0[8]={0,0,0,0,0,0,0,0}, s1[8]={0,0,0,0,0,0,0,0};
  float q0[8]={0,0,0,0,0,0,0,0}, q1[8]={0,0,0,0,0,0,0,0};
  for(int e4 = wid*4; e4 < N_ENT; e4 += nw*4){
    int e = e4 + g;
    uint4 u = *(const uint4*)(entnbf + (size_t)e*64 + l16*4);
    float w0 = (float)cnt0[e], w1 = (float)cnt1[e];
    float v[8] = {bfl(u.x),bfh(u.x),bfl(u.y),bfh(u.y),
                  bfl(u.z),bfh(u.z),bfl(u.w),bfh(u.w)};
    #pragma unroll
    for(int k=0;k<8;k++){
      s0[k] += w0*v[k]; s1[k] += w1*v[k];
      q0[k] += w0*v[k]*v[k]; q1[k] += w1*v[k]*v[k];
    }
  }
  #pragma unroll
  for(int k=0;k<8;k++){
    int c = l16*8 + k;
    atomicAdd(&acc[c],     s0[k]);
    atomicAdd(&acc[128+c], s1[k]);
    atomicAdd(&acc[256+c], q0[k]);
    atomicAdd(&acc[384+c], q1[k]);
  }
  __syncthreads();
  pstat[(size_t)blockIdx.x*512 + t]       = acc[t];
  pstat[(size_t)blockIdx.x*512 + 256 + t] = acc[t+256];
}

// ------- K2c: reduce stat partials into stats[0..512): 64 blocks ------------
__global__ __launch_bounds__(256) void k_redstats(const float* __restrict__ pstat,
    float* __restrict__ stats){
  int tid = blockIdx.x*256 + threadIdx.x;     // 64*256 = 16384 threads
  int c = tid & 511;
  int chunk = tid >> 9;                       // 0..31
  float s = 0.f;
  #pragma unroll 4
  for(int k=0;k<STAT_BLKS/32;k++)
    s += pstat[(size_t)(chunk*(STAT_BLKS/32) + k)*512 + c];
  atomicAdd(&stats[c], s);
}

// ------- K3: per-rel scale + Qr stats (LDS-aggregated) + phase tables -------
__global__ __launch_bounds__(256) void k_relstats(const float* __restrict__ rel,
    const int* __restrict__ cntr, float* __restrict__ scale_rel,
    float* __restrict__ stats, float* __restrict__ cosr, float* __restrict__ sinr){
  __shared__ float qacc[128];
  int t = threadIdx.x, lane = t & 63;
  if(t < 128) qacc[t] = 0.f;
  __syncthreads();
  int r = blockIdx.x*4 + (t>>6);
  if(r < N_REL){
    float2 x = *(const float2*)(rel + (size_t)r*D + 2*lane);
    float ss = x.x*x.x + x.y*x.y;
    #pragma unroll
    for(int o=32;o>0;o>>=1) ss += __shfl_xor(ss,o,64);
    float nrm = sqrtf(ss);
    float sc = nrm > 1.0f ? 1.0f/nrm : 1.0f;
    if(lane==0) scale_rel[r] = sc;
    float w = (float)cntr[r];
    float sx = x.x*sc, sy = x.y*sc;
    atomicAdd(&qacc[2*lane  ], w*sx*sx);
    atomicAdd(&qacc[2*lane+1], w*sy*sy);
    if(lane < 32){
      cosr[r*64 + 2*lane  ] = cosf(x.x*PHASE_C);
      sinr[r*64 + 2*lane  ] = sinf(x.x*PHASE_C);
      cosr[r*64 + 2*lane+1] = cosf(x.y*PHASE_C);
      sinr[r*64 + 2*lane+1] = sinf(x.y*PHASE_C);
    }
  }
  __syncthreads();
  if(t < 128) atomicAdd(&stats[512+t], qacc[t]);
}

// ------- K4: finalize BN0, build folded bf16 weights Wbf, W2 and b' ---------
__global__ __launch_bounds__(384) void k_bn0fin(const float* __restrict__ stats,
    const float* __restrict__ W_a, const float* __restrict__ b_a,
    const float* __restrict__ gamma0, const float* __restrict__ beta0,
    u16* __restrict__ Wbf, float* __restrict__ W2, float* __restrict__ bprime){
  __shared__ float a0[384], c0[384];
  int t = threadIdx.x;
  {
    int j = t & 127;
    float mu, ex2;
    if(t < 256){
      mu  = (stats[j]     + stats[128+j]) * (1.0f/(2.0f*N_TRIP));
      ex2 = (stats[256+j] + stats[384+j]) * (1.0f/(2.0f*N_TRIP));
    } else {
      mu  = 0.0f;
      ex2 = stats[512+j] * (1.0f/N_TRIP);
    }
    float var = ex2 - mu*mu;
    float a = gamma0[t]*rsqrtf(var + BN_EPSF);
    a0[t] = a;
    c0[t] = beta0[t] - mu*a;
  }
  __syncthreads();
  for(int idx=t; idx<256*128; idx+=384){
    int j = idx>>7, k = idx&127;
    int ko = ((j>>7)<<7) + k;
    Wbf[idx] = f2bf(W_a[(j&127)*384 + ko]*a0[ko]);
  }
  for(int idx=t; idx<128*128; idx+=384){
    int k = idx>>7, j = idx&127;
    W2[idx] = W_a[j*384 + 256 + k]*a0[256+k];
  }
  if(t < 128){
    float s = b_a[t];
    for(int k=0;k<384;k++) s += W_a[t*384+k]*c0[k];
    bprime[t] = s;
  }
}

// ------- K5: R[r] = rel_n[r] @ W2 ------------------------------------------
__global__ __launch_bounds__(128) void k_relproj(const float* __restrict__ rel,
    const float* __restrict__ scale_rel, const float* __restrict__ W2,
    float* __restrict__ R){
  int r = blockIdx.x, j = threadIdx.x;
  __shared__ float x[128];
  x[j] = rel[(size_t)r*D + j]*scale_rel[r];
  __syncthreads();
  float s = 0.f;
  for(int k=0;k<128;k++) s += x[k]*W2[k*128+j];
  R[r*128+j] = s;
}

// ------- K6: A/B projection via MFMA; input is pre-normalized bf16 ----------
__global__ __launch_bounds__(256) void k_ab(const u32* __restrict__ entnbf,
    const u16* __restrict__ Wbf, u16* __restrict__ Abuf, u16* __restrict__ Bbuf){
  __shared__ u16 xlds[16*128];
  int t = threadIdx.x, lane = t & 63, q = t >> 6;
  int kgrp = (lane>>4)<<3;
  int rgrp = (lane>>4)<<2;
  int frow = lane & 15;
  short8 wf[4][4];
  #pragma unroll
  for(int jt=0;jt<4;jt++){
    #pragma unroll
    for(int kt=0;kt<4;kt++)
      wf[jt][kt] = *(const short8*)(Wbf + (size_t)(q*64 + jt*16 + frow)*D + kgrp + kt*32);
  }
  int srow = t>>4;
  int scol16 = t&15;
  char* swp = (char*)xlds + srow*256 + ((scol16<<4) ^ ((srow&7)<<4));
  const char* rdp = (const char*)xlds + frow*256;
  int rbase0 = (lane>>4)<<4;
  int fsw = (frow&7)<<4;
  for(int chunk = blockIdx.x; chunk < N_ENT/16; chunk += gridDim.x){
    uint4 pk = *(const uint4*)(entnbf + (size_t)(chunk*16 + srow)*64 + scol16*4);
    __syncthreads();
    *(uint4*)swp = pk;
    __syncthreads();
    short8 xf[4];
    #pragma unroll
    for(int kt=0;kt<4;kt++)
      xf[kt] = *(const short8*)(rdp + ((rbase0 + kt*64) ^ fsw));
    int erow = chunk*16 + frow;
    #pragma unroll
    for(int jt=0;jt<4;jt++){
      f32x4 acc = {0.f,0.f,0.f,0.f};
      #pragma unroll
      for(int kt=0;kt<4;kt++)
        acc = __builtin_amdgcn_mfma_f32_16x16x32_bf16(wf[jt][kt], xf[kt], acc, 0,0,0);
      int jbase = q*64 + jt*16 + rgrp;
      u16x4 opk;
      opk.x=f2bf(acc[0]); opk.y=f2bf(acc[1]); opk.z=f2bf(acc[2]); opk.w=f2bf(acc[3]);
      u16* dst = (jbase < 128) ? (Abuf + (size_t)erow*D + jbase)
                               : (Bbuf + (size_t)erow*D + (jbase-128));
      *(u16x4*)dst = opk;
    }
  }
}

// ------- K7: BN1 stats, 1/4 subsample, partials to scratch (no atomics) -----
__global__ __launch_bounds__(256) void k_bn1stats(const u64* __restrict__ pair64,
    const u16* __restrict__ A, const u16* __restrict__ B,
    const float* __restrict__ R, const float* __restrict__ bprime,
    float* __restrict__ pstat1){
  __shared__ float acc[256];
  int t = threadIdx.x;
  acc[t] = 0.f;
  __syncthreads();
  int lane = t & 63;
  int gw = blockIdx.x*4 + (t>>6), nw = gridDim.x*4;
  float bp0 = bprime[2*lane], bp1 = bprime[2*lane+1];
  float s0=0,s1=0,q0=0,q1=0;
  for(int i=4*gw; i<N_TRIP; i+=8*nw){
    {
      u64 pr = pair64[i];
      int t0 = (int)(pr & 0x3FFFF);
      int t1 = (int)((pr>>18) & 0x3FFFF);
      int t2 = (int)(pr>>36);
      u32 ua0 = *(const u32*)(A + (size_t)t0*D + 2*lane);
      u32 ua1 = *(const u32*)(A + (size_t)t1*D + 2*lane);
      u32 ub0 = *(const u32*)(B + (size_t)t0*D + 2*lane);
      u32 ub1 = *(const u32*)(B + (size_t)t1*D + 2*lane);
      float2 r = *(const float2*)(R + (size_t)t2*D + 2*lane);
      float y1x = bfl(ua0)+bfl(ub1)+r.x+bp0;
      float y1y = bfh(ua0)+bfh(ub1)+r.y+bp1;
      float y2x = bfl(ua1)+bfl(ub0)-r.x+bp0;
      float y2y = bfh(ua1)+bfh(ub0)-r.y+bp1;
      s0 += y1x+y2x; s1 += y1y+y2y;
      q0 += y1x*y1x + y2x*y2x; q1 += y1y*y1y + y2y*y2y;
    }
    int i2 = i + 4*nw;
    if(i2 < N_TRIP){
      u64 pr = pair64[i2];
      int t0 = (int)(pr & 0x3FFFF);
      int t1 = (int)((pr>>18) & 0x3FFFF);
      int t2 = (int)(pr>>36);
      u32 ua0 = *(const u32*)(A + (size_t)t0*D + 2*lane);
      u32 ua1 = *(const u32*)(A + (size_t)t1*D + 2*lane);
      u32 ub0 = *(const u32*)(B + (size_t)t0*D + 2*lane);
      u32 ub1 = *(const u32*)(B + (size_t)t1*D + 2*lane);
      float2 r = *(const float2*)(R + (size_t)t2*D + 2*lane);
      float y1x = bfl(ua0)+bfl(ub1)+r.x+bp0;
      float y1y = bfh(ua0)+bfh(ub1)+r.y+bp1;
      float y2x = bfl(ua1)+bfl(ub0)-r.x+bp0;
      float y2y = bfh(ua1)+bfh(ub0)-r.y+bp1;
      s0 += y1x+y2x; s1 += y1y+y2y;
      q0 += y1x*y1x + y2x*y2x; q1 += y1y*y1y + y2y*y2y;
    }
  }
  atomicAdd(&acc[      2*lane  ], s0);
  atomicAdd(&acc[      2*lane+1], s1);
  atomicAdd(&acc[128 + 2*lane  ], q0);
  atomicAdd(&acc[128 + 2*lane+1], q1);
  __syncthreads();
  pstat1[(size_t)blockIdx.x*256 + t] = acc[t];
}

// ------- K8: reduce BN1 partials + finalize + u-vectors ---------------------
// a1c layout: [0:128)=a1 [128:256)=cc [256:384)=wa1 [384]=kap
//             [512:640)=uA = W'_A^T wa1   [640:768)=uB = W'_B^T wa1
__global__ __launch_bounds__(128) void k_bn1fin(const float* __restrict__ pstat1,
    const float* __restrict__ gamma1, const float* __restrict__ beta1,
    const float* __restrict__ W_a2, const float* __restrict__ b_a2,
    const float* __restrict__ bprime, const u16* __restrict__ Wbf,
    float* __restrict__ a1c){
  __shared__ float red[128];
  __shared__ float swa1[128];
  int j = threadIdx.x;
  float s = 0.f, q = 0.f;
  for(int b=0;b<BN1_BLKS;b++){
    s += pstat1[(size_t)b*256 + j];
    q += pstat1[(size_t)b*256 + 128 + j];
  }
  float mu  = s*(2.0f/(float)N_TRIP);
  float var = q*(2.0f/(float)N_TRIP) - mu*mu;
  float a = gamma1[j]*rsqrtf(var + BN_EPSF);
  float cc = beta1[j] - mu*a;
  float wa1 = W_a2[j]*a;
  a1c[j]     = a;
  a1c[128+j] = cc;
  a1c[256+j] = wa1;
  swa1[j] = wa1;
  red[j] = W_a2[j]*cc + wa1*bprime[j];
  __syncthreads();
  float uA = 0.f, uB = 0.f;
  for(int jj=0; jj<128; jj++){
    float w = swa1[jj];
    uA += w*bfu(Wbf[jj*D + j]);
    uB += w*bfu(Wbf[(128+jj)*D + j]);
  }
  a1c[512+j] = uA;
  a1c[640+j] = uB;
  #pragma unroll
  for(int st=64; st>0; st>>=1){
    if(j < st) red[j] += red[j+st];
    __syncthreads();
  }
  if(j==0) a1c[384] = red[0] + b_a2[0];
}

// ------- K8b: per-entity scalars from entnbf via u-vectors (half traffic) ---
__global__ __launch_bounds__(256) void k_alphabeta(const u32* __restrict__ entnbf,
    const float* __restrict__ R, const float* __restrict__ a1c,
    float* __restrict__ alpha, float* __restrict__ beta, float* __restrict__ rho){
  int t = threadIdx.x, lane = t & 63;
  int l16 = lane & 15, g = lane >> 4;
  int wid = blockIdx.x*4 + (t>>6), nw = gridDim.x*4;
  int cb = l16*8;
  float4 uA0 = *(const float4*)(a1c + 512 + cb);
  float4 uA1 = *(const float4*)(a1c + 512 + cb + 4);
  float4 uB0 = *(const float4*)(a1c + 640 + cb);
  float4 uB1 = *(const float4*)(a1c + 640 + cb + 4);
  for(int e4 = wid*4; e4 < N_ENT; e4 += nw*4){
    int e = e4 + g;
    uint4 u = *(const uint4*)(entnbf + (size_t)e*64 + l16*4);
    float v0=bfl(u.x), v1=bfh(u.x), v2=bfl(u.y), v3=bfh(u.y);
    float v4=bfl(u.z), v5=bfh(u.z), v6=bfl(u.w), v7=bfh(u.w);
    float da = v0*uA0.x + v1*uA0.y + v2*uA0.z + v3*uA0.w
             + v4*uA1.x + v5*uA1.y + v6*uA1.z + v7*uA1.w;
    float db = v0*uB0.x + v1*uB0.y + v2*uB0.z + v3*uB0.w
             + v4*uB1.x + v5*uB1.y + v6*uB1.z + v7*uB1.w;
    #pragma unroll
    for(int o=8;o>0;o>>=1){
      da += __shfl_xor(da,o,64);
      db += __shfl_xor(db,o,64);
    }
    if(l16==0){ alpha[e]=da; beta[e]=db; }
  }
  float4 w0 = *(const float4*)(a1c + 256 + cb);
  float4 w1 = *(const float4*)(a1c + 256 + cb + 4);
  for(int r4 = wid*4; r4 < N_REL; r4 += nw*4){
    int r = r4 + g;
    if(r < N_REL){
      float4 rA = *(const float4*)(R + (size_t)r*D + cb);
      float4 rB = *(const float4*)(R + (size_t)r*D + cb + 4);
      float dr = rA.x*w0.x + rA.y*w0.y + rA.z*w0.z + rA.w*w0.w
               + rB.x*w1.x + rB.y*w1.y + rB.z*w1.z + rB.w*w1.w;
      #pragma unroll
      for(int o=8;o>0;o>>=1) dr += __shfl_xor(dr,o,64);
      if(l16==0) rho[r]=dr;
    }
  }
}

// ------- K9: per-entity gather, 16-lane groups, x2 edge unroll --------------
__global__ __launch_bounds__(256) void k_ent(
    const int* __restrict__ offs, const int* __restrict__ endp,
    const u32* __restrict__ ebuf,
    const u16* __restrict__ A, const u16* __restrict__ B,
    const float* __restrict__ R, const float* __restrict__ bprime,
    const float* __restrict__ a1c, const float* __restrict__ alpha,
    const float* __restrict__ beta, const float* __restrict__ rho,
    float* __restrict__ out_hent){
  int t = threadIdx.x, lane = t & 63;
  int l16 = lane & 15, g = lane >> 4;
  int wid = blockIdx.x*4 + (t>>6), nw = gridDim.x*4;
  int cb = l16*8;
  float4 bpA = *(const float4*)(bprime + cb);
  float4 bpB = *(const float4*)(bprime + cb + 4);
  float4 a1A = *(const float4*)(a1c + cb);
  float4 a1B = *(const float4*)(a1c + cb + 4);
  float4 ccA = *(const float4*)(a1c + 128 + cb);
  float4 ccB = *(const float4*)(a1c + 128 + cb + 4);
  float kap = a1c[384];
  for(int e4 = wid*4; e4 < N_ENT; e4 += nw*4){
    int e = e4 + g;
    int s = offs[e], en = endp[e];
    uint4 ua = *(const uint4*)(A + (size_t)e*D + cb);
    float ax0 = bfl(ua.x), ax1 = bfh(ua.x), ax2 = bfl(ua.y), ax3 = bfh(ua.y);
    float ax4 = bfl(ua.z), ax5 = bfh(ua.z), ax6 = bfl(ua.w), ax7 = bfh(ua.w);
    float al = alpha[e];
    float h0=0,h1=0,h2=0,h3=0,h4=0,h5=0,h6=0,h7=0, eb=0;
    int o = s;
    for(; o+1<en; o+=2){
      u32 idX = ebuf[o], idY = ebuf[o+1];
      int otX = idX>>10, r2X = (idX>>1)&511;
      int otY = idY>>10, r2Y = (idY>>1)&511;
      float sgX = (idX&1) ? -1.f : 1.f;
      float sgY = (idY&1) ? -1.f : 1.f;
      uint4 ubX = *(const uint4*)(B + (size_t)otX*D + cb);
      uint4 ubY = *(const uint4*)(B + (size_t)otY*D + cb);
      float4 rAX = *(const float4*)(R + (size_t)r2X*D + cb);
      float4 rBX = *(const float4*)(R + (size_t)r2X*D + cb + 4);
      float4 rAY = *(const float4*)(R + (size_t)r2Y*D + cb);
      float4 rBY = *(const float4*)(R + (size_t)r2Y*D + cb + 4);
      float beX = beta[otX], beY = beta[otY];
      float roX = rho[r2X],  roY = rho[r2Y];
      float svX = al + beX + sgX*roX + kap;
      float svY = al + beY + sgY*roY + kap;
      float ebX = expf(svX >= 0.f ? -svX : -0.01f*svX);
      float ebY = expf(svY >= 0.f ? -svY : -0.01f*svY);
      float y, c;
      y = ax0 + bfl(ubX.x) + sgX*rAX.x + bpA.x; c = y*a1A.x + ccA.x; h0 += ebX*c;
      y = ax1 + bfh(ubX.x) + sgX*rAX.y + bpA.y; c = y*a1A.y + ccA.y; h1 += ebX*c;
      y = ax2 + bfl(ubX.y) + sgX*rAX.z + bpA.z; c = y*a1A.z + ccA.z; h2 += ebX*c;
      y = ax3 + bfh(ubX.y) + sgX*rAX.w + bpA.w; c = y*a1A.w + ccA.w; h3 += ebX*c;
      y = ax4 + bfl(ubX.z) + sgX*rBX.x + bpB.x; c = y*a1B.x + ccB.x; h4 += ebX*c;
      y = ax5 + bfh(ubX.z) + sgX*rBX.y + bpB.y; c = y*a1B.y + ccB.y; h5 += ebX*c;
      y = ax6 + bfl(ubX.w) + sgX*rBX.z + bpB.z; c = y*a1B.z + ccB.z; h6 += ebX*c;
      y = ax7 + bfh(ubX.w) + sgX*rBX.w + bpB.w; c = y*a1B.w + ccB.w; h7 += ebX*c;
      y = ax0 + bfl(ubY.x) + sgY*rAY.x + bpA.x; c = y*a1A.x + ccA.x; h0 += ebY*c;
      y = ax1 + bfh(ubY.x) + sgY*rAY.y + bpA.y; c = y*a1A.y + ccA.y; h1 += ebY*c;
      y = ax2 + bfl(ubY.y) + sgY*rAY.z + bpA.z; c = y*a1A.z + ccA.z; h2 += ebY*c;
      y = ax3 + bfh(ubY.y) + sgY*rAY.w + bpA.w; c = y*a1A.w + ccA.w; h3 += ebY*c;
      y = ax4 + bfl(ubY.z) + sgY*rBY.x + bpB.x; c = y*a1B.x + ccB.x; h4 += ebY*c;
      y = ax5 + bfh(ubY.z) + sgY*rBY.y + bpB.y; c = y*a1B.y + ccB.y; h5 += ebY*c;
      y = ax6 + bfl(ubY.w) + sgY*rBY.z + bpB.z; c = y*a1B.z + ccB.z; h6 += ebY*c;
      y = ax7 + bfh(ubY.w) + sgY*rBY.w + bpB.w; c = y*a1B.w + ccB.w; h7 += ebY*c;
      eb += ebX + ebY;
    }
    if(o < en){
      u32 id = ebuf[o];
      int ot = id>>10, r2 = (id>>1)&511;
      float sg = (id&1) ? -1.f : 1.f;
      uint4 ub = *(const uint4*)(B + (size_t)ot*D + cb);
      float4 rA = *(const float4*)(R + (size_t)r2*D + cb);
      float4 rB = *(const float4*)(R + (size_t)r2*D + cb + 4);
      float sv = al + beta[ot] + sg*rho[r2] + kap;
      float e_b = expf(sv >= 0.f ? -sv : -0.01f*sv);
      float y, c;
      y = ax0 + bfl(ub.x) + sg*rA.x + bpA.x; c = y*a1A.x + ccA.x; h0 += e_b*c;
      y = ax1 + bfh(ub.x) + sg*rA.y + bpA.y; c = y*a1A.y + ccA.y; h1 += e_b*c;
      y = ax2 + bfl(ub.y) + sg*rA.z + bpA.z; c = y*a1A.z + ccA.z; h2 += e_b*c;
      y = ax3 + bfh(ub.y) + sg*rA.w + bpA.w; c = y*a1A.w + ccA.w; h3 += e_b*c;
      y = ax4 + bfl(ub.z) + sg*rB.x + bpB.x; c = y*a1B.x + ccB.x; h4 += e_b*c;
      y = ax5 + bfh(ub.z) + sg*rB.y + bpB.y; c = y*a1B.y + ccB.y; h5 += e_b*c;
      y = ax6 + bfl(ub.w) + sg*rB.z + bpB.z; c = y*a1B.z + ccB.z; h6 += e_b*c;
      y = ax7 + bfh(ub.w) + sg*rB.w + bpB.w; c = y*a1B.w + ccB.w; h7 += e_b*c;
      eb += e_b;
    }
    float inv = (en > s) ? 1.0f/eb : 0.0f;
    float4 o0; o0.x=h0*inv; o0.y=h1*inv; o0.z=h2*inv; o0.w=h3*inv;
    float4 o1; o1.x=h4*inv; o1.y=h5*inv; o1.z=h6*inv; o1.w=h7*inv;
    *(float4*)(out_hent + (size_t)e*D + cb)     = o0;
    *(float4*)(out_hent + (size_t)e*D + cb + 4) = o1;
  }
}

// ------- K10: per-rel gather pass, packed pairs, x2 unrolled ----------------
__global__ __launch_bounds__(512) void k_rel(
    const int* __restrict__ roffs, const int* __restrict__ cntr,
    const u64* __restrict__ rpair,
    const u16* __restrict__ A, const u16* __restrict__ B,
    const float* __restrict__ R, const float* __restrict__ bprime,
    const float* __restrict__ a1c, const float* __restrict__ alpha,
    const float* __restrict__ beta, const float* __restrict__ rho,
    float* __restrict__ out_hrel){
  __shared__ float red[8][128];
  int t = threadIdx.x, lane = t & 63, w = t >> 6;
  int r = blockIdx.x;
  int cnt = cntr[r], base = roffs[r];
  float2 rr = *(const float2*)(R + (size_t)r*D + 2*lane);
  float bp0 = bprime[2*lane], bp1 = bprime[2*lane+1];
  float a1x = a1c[2*lane],     a1y = a1c[2*lane+1];
  float ccx = a1c[128+2*lane], ccy = a1c[128+2*lane+1];
  float kap = a1c[384];
  float rhor = rho[r];
  float sx = 0.f, sy = 0.f;
  for(int j=w; j<cnt; j+=16){
    {
      u64 pr = rpair[base+j];
      int t0 = (int)(pr & 0x3FFFF);
      int t1 = (int)((pr>>18) & 0x3FFFF);
      float s1 = alpha[t0] + beta[t1] + rhor + kap;
      float s2 = alpha[t1] + beta[t0] - rhor + kap;
      float e1 = expf(s1 >= 0.f ? -s1 : -0.01f*s1);
      float e2 = expf(s2 >= 0.f ? -s2 : -0.01f*s2);
      u32 ua0 = *(const u32*)(A + (size_t)t0*D + 2*lane);
      u32 ua1 = *(const u32*)(A + (size_t)t1*D + 2*lane);
      u32 ub0 = *(const u32*)(B + (size_t)t0*D + 2*lane);
      u32 ub1 = *(const u32*)(B + (size_t)t1*D + 2*lane);
      float y1x = bfl(ua0)+bfl(ub1)+rr.x+bp0;
      float y1y = bfh(ua0)+bfh(ub1)+rr.y+bp1;
      float y2x = bfl(ua1)+bfl(ub0)-rr.x+bp0;
      float y2y = bfh(ua1)+bfh(ub0)-rr.y+bp1;
      float c1x = y1x*a1x+ccx, c1y = y1y*a1y+ccy;
      float c2x = y2x*a1x+ccx, c2y = y2y*a1y+ccy;
      sx += e1*c1x - e2*c2x;
      sy += e1*c1y - e2*c2y;
    }
    int j2 = j + 8;
    if(j2 < cnt){
      u64 pr = rpair[base+j2];
      int t0 = (int)(pr & 0x3FFFF);
      int t1 = (int)((pr>>18) & 0x3FFFF);
      float s1 = alpha[t0] + beta[t1] + rhor + kap;
      float s2 = alpha[t1] + beta[t0] - rhor + kap;
      float e1 = expf(s1 >= 0.f ? -s1 : -0.01f*s1);
      float e2 = expf(s2 >= 0.f ? -s2 : -0.01f*s2);
      u32 ua0 = *(const u32*)(A + (size_t)t0*D + 2*lane);
      u32 ua1 = *(const u32*)(A + (size_t)t1*D + 2*lane);
      u32 ub0 = *(const u32*)(B + (size_t)t0*D + 2*lane);
      u32 ub1 = *(const u32*)(B + (size_t)t1*D + 2*lane);
      float y1x = bfl(ua0)+bfl(ub1)+rr.x+bp0;
      float y1y = bfh(ua0)+bfh(ub1)+rr.y+bp1;
      float y2x = bfl(ua1)+bfl(ub0)-rr.x+bp0;
      float y2y = bfh(ua1)+bfh(ub0)-rr.y+bp1;
      float c1x = y1x*a1x+ccx, c1y = y1y*a1y+ccy;
      float c2x = y2x*a1x+ccx, c2y = y2y*a1y+ccy;
      sx += e1*c1x - e2*c2x;
      sy += e1*c1y - e2*c2y;
    }
  }
  float2 p; p.x = sx; p.y = sy;
  *(float2*)&red[w][2*lane] = p;
  __syncthreads();
  if(t < 128){
    float s = 0.f;
    #pragma unroll
    for(int k=0;k<8;k++) s += red[k][t];
    float cf = cnt > 0 ? (float)cnt : 1.0f;
    out_hrel[(size_t)r*D + t] = s/cf;
  }
}

// ------- K12: RotatE score, fp32 gathers, 16-lane groups --------------------
__global__ __launch_bounds__(256) void k_score(const u64* __restrict__ pair64,
    const float* __restrict__ ent, const float* __restrict__ cosr,
    const float* __restrict__ sinr, float* __restrict__ score){
  int t = threadIdx.x, lane = t & 63;
  int l16 = lane & 15, g = lane >> 4;
  int wid = blockIdx.x*4 + (t>>6), nw = gridDim.x*4;
  for(int i4 = wid*4; i4 < N_TRIP; i4 += nw*4){
    int i = i4 + g;
    u64 pr = pair64[i];
    int t0 = (int)(pr & 0x3FFFF);
    int t1 = (int)((pr>>18) & 0x3FFFF);
    int t2 = (int)(pr>>36);
    float4 rh = *(const float4*)(ent + (size_t)t0*D + l16*4);
    float4 ih = *(const float4*)(ent + (size_t)t0*D + 64 + l16*4);
    float4 rt = *(const float4*)(ent + (size_t)t1*D + l16*4);
    float4 it = *(const float4*)(ent + (size_t)t1*D + 64 + l16*4);
    float4 cr = *(const float4*)(cosr + (size_t)t2*64 + l16*4);
    float4 sr = *(const float4*)(sinr + (size_t)t2*64 + l16*4);
    float rha[4] = {rh.x,rh.y,rh.z,rh.w};
    float iha[4] = {ih.x,ih.y,ih.z,ih.w};
    float rta[4] = {rt.x,rt.y,rt.z,rt.w};
    float ita[4] = {it.x,it.y,it.z,it.w};
    float cca[4] = {cr.x,cr.y,cr.z,cr.w};
    float ssa[4] = {sr.x,sr.y,sr.z,sr.w};
    float d = 0.f;
    #pragma unroll
    for(int k=0;k<4;k++){
      float res = cca[k]*rta[k] + ssa[k]*ita[k] - rha[k];
      float ims = cca[k]*ita[k] - ssa[k]*rta[k] - iha[k];
      d += sqrtf(res*res + ims*ims);
    }
    #pragma unroll
    for(int o=8;o>0;o>>=1) d += __shfl_xor(d,o,64);
    if(l16==0) score[i] = MARGINF - d;
  }
}

extern "C" void kernel_launch(void* const* d_in, const int* in_sizes, int n_in,
                              void* d_out, int out_size, void* d_ws, size_t ws_size,
                              hipStream_t stream){
  const int*   trip   = (const int*)  d_in[0];
  const float* ent    = (const float*)d_in[1];
  const float* rel    = (const float*)d_in[2];
  const float* W_a    = (const float*)d_in[3];
  const float* b_a    = (const float*)d_in[4];
  const float* W_a2   = (const float*)d_in[5];
  const float* b_a2   = (const float*)d_in[6];
  const float* gamma0 = (const float*)d_in[7];
  const float* beta0  = (const float*)d_in[8];
  const float* gamma1 = (const float*)d_in[9];
  const float* beta1  = (const float*)d_in[10];

  char* ws = (char*)d_ws;
  size_t off = 0;
  auto take = [&](size_t bytes)->void*{
    void* p = ws + off;
    off += (bytes + 255) & ~(size_t)255;
    return p;
  };
  // ---- zeroed scratch (contiguous from 0) ----
  int*   cnt0    = (int*)  take((size_t)N_ENT*4);
  int*   cnt1    = (int*)  take((size_t)N_ENT*4);
  int*   cntr    = (int*)  take((size_t)N_REL*4);
  float* stats   = (float*)take(640*4);
  size_t zero_bytes = off;
  // ---- fully-overwritten scratch ----
  int*   offs      = (int*)  take((size_t)N_ENT*4);
  int*   cur       = (int*)  take((size_t)N_ENT*4);
  int*   bsum      = (int*)  take(512*4);
  int*   boffs     = (int*)  take(512*4);
  int*   roffs     = (int*)  take(512*4);
  int*   rcur      = (int*)  take(512*4);
  u32*   ebuf      = (u32*)  take((size_t)2*N_TRIP*4);
  u64*   pair64    = (u64*)  take((size_t)N_TRIP*8);
  u64*   rpair     = (u64*)  take((size_t)N_TRIP*8);
  float* scale_rel = (float*)take((size_t)N_REL*4);
  u16*   Wbf       = (u16*)  take(256*128*2);
  float* W2        = (float*)take(128*128*4);
  float* bprime    = (float*)take(128*4);
  float* a1c       = (float*)take(768*4);
  float* R         = (float*)take((size_t)N_REL*D*4);
  float* cosr      = (float*)take((size_t)N_REL*64*4);
  float* sinr      = (float*)take((size_t)N_REL*64*4);
  float* alpha     = (float*)take((size_t)N_ENT*4);
  float* betab     = (float*)take((size_t)N_ENT*4);
  float* rho       = (float*)take(512*4);
  float* pstat     = (float*)take((size_t)STAT_BLKS*512*4);
  float* pstat1    = (float*)take((size_t)BN1_BLKS*256*4);
  u16*   Abuf      = (u16*)  take((size_t)N_ENT*D*2);
  u16*   Bbuf      = (u16*)  take((size_t)N_ENT*D*2);
  u32*   entnbf    = (u32*)  take((size_t)N_ENT*64*4);
  (void)ws_size; (void)n_in; (void)in_sizes; (void)out_size;

  float* out_hent  = (float*)d_out;
  float* out_hrel  = out_hent + (size_t)N_ENT*D;
  float* out_score = out_hrel + (size_t)N_REL*D;

  hipMemsetAsync(d_ws, 0, zero_bytes, stream);

  const int SCAN_BLKS = (N_ENT + 1023)/1024;     // 196
  const int EDG_BLKS  = (N_TRIP + 2047)/2048;    // 98
  k_hist     <<<EDG_BLKS, 256, 0, stream>>>(trip, cnt0, cnt1, cntr);
  k_prep     <<<2048, 256, 0, stream>>>(ent, entnbf);
  k_stats    <<<STAT_BLKS, 256, 0, stream>>>(entnbf, cnt0, cnt1, pstat);
  k_redstats <<<64, 256, 0, stream>>>(pstat, stats);
  k_scan1    <<<SCAN_BLKS, 1024, 0, stream>>>(cnt0, cnt1, offs, bsum);
  k_scan2    <<<1, 512, 0, stream>>>(bsum, boffs, cntr, roffs, rcur, SCAN_BLKS);
  k_scan3    <<<SCAN_BLKS, 1024, 0, stream>>>(offs, boffs, cur);
  k_edges    <<<EDG_BLKS, 256, 0, stream>>>(trip, cur, rcur, ebuf, pair64, rpair);
  k_relstats <<<(N_REL+3)/4, 256, 0, stream>>>(rel, cntr, scale_rel, stats, cosr, sinr);
  k_bn0fin   <<<1, 384, 0, stream>>>(stats, W_a, b_a, gamma0, beta0, Wbf, W2, bprime);
  k_relproj  <<<N_REL, 128, 0, stream>>>(rel, scale_rel, W2, R);
  k_ab       <<<2048, 256, 0, stream>>>(entnbf, Wbf, Abuf, Bbuf);
  k_bn1stats <<<BN1_BLKS, 256, 0, stream>>>(pair64, Abuf, Bbuf, R, bprime, pstat1);
  k_bn1fin   <<<1, 128, 0, stream>>>(pstat1, gamma1, beta1, W_a2, b_a2, bprime, Wbf, a1c);
  k_alphabeta<<<2048, 256, 0, stream>>>(entnbf, R, a1c, alpha, betab, rho);
  k_ent      <<<2048, 256, 0, stream>>>(offs, cur, ebuf, Abuf, Bbuf, R,
                                        bprime, a1c, alpha, betab, rho, out_hent);
  k_rel      <<<N_REL, 512, 0, stream>>>(roffs, cntr, rpair, Abuf, Bbuf, R,
                                         bprime, a1c, alpha, betab, rho, out_hrel);
  k_score    <<<2048, 256, 0, stream>>>(pair64, ent, cosr, sinr, out_score);
}